// Round 7
// baseline (22.357 us; speedup 1.0000x reference)
//
#include <hip/hip_runtime.h>
#include <cstdint>
#include <cstddef>

#define B_ 32
#define V_ 8
#define S_ 4096
#define E_ 64
#define T_ 1020     // len(arange(0, S-WIN, STEP))
#define TT 32       // tokens per block
#define SLP 200     // e-tile row stride (need >=140 cols)

typedef __bf16 bf16_t;
typedef bf16_t bf16x8 __attribute__((ext_vector_type(8)));
typedef float f32x16 __attribute__((ext_vector_type(16)));

// ---- prep: w2sw so a wave's 32x32x16 B-fragment is one coalesced 1KB load ----
// elem ((kk*2 + nh)*64 + l)*8 + j  =  W2[f = 16*kk + 8*(l>>5) + j][n = 32*nh + (l&31)]
__global__ __launch_bounds__(256) void prep_kernel(const float* __restrict__ W2,
                                                   bf16_t* __restrict__ w2sw) {
  const int q = blockIdx.x * 256 + threadIdx.x;      // 8192 quads of 8 elems
  const int l = q & 63, nh = (q >> 6) & 1, kk = q >> 7;
  const int fb = 16 * kk + 8 * (l >> 5);
  const int n = 32 * nh + (l & 31);
  bf16x8 v;
#pragma unroll
  for (int j = 0; j < 8; ++j) v[j] = (bf16_t)W2[(fb + j) * E_ + n];
  *reinterpret_cast<bf16x8*>(w2sw + (size_t)q * 8) = v;
}

// ---- fused: e-tile build (LDS) + barrier-free 32x32x16 K-loop, K split across wave pairs ----
// Block (t0,b): 32 tok x 64 n; wave (nh,kh): 32 tok x 32 n x 512 k. kh-pair reduces via LDS.
__global__ __launch_bounds__(256, 4) void fused_kernel(const float* __restrict__ x,
                                                       const float* __restrict__ W1,
                                                       const float* __restrict__ b1,
                                                       const bf16_t* __restrict__ w2sw,
                                                       const float* __restrict__ b2,
                                                       float* __restrict__ out) {
  __shared__ bf16_t et[E_ * SLP];   // 25.6 KB; first 8 KB reused as f32 reduce buffer
  const int tid = threadIdx.x;
  const int b = blockIdx.y;
  const int t0 = blockIdx.x * TT;
  // ---- e-build: thread = (d-group of 8, s-lane of 32) x 5 slots; W1/b1 via L1 broadcast ----
  {
    const int dg = tid >> 5;
    const int sg = tid & 31;
    const int s0 = 4 * t0;
    float xv[V_][5];
#pragma unroll
    for (int v = 0; v < V_; ++v) {
#pragma unroll
      for (int k = 0; k < 5; ++k) {
        int s = s0 + sg + 32 * k;
        if (s > S_ - 1) s = S_ - 1;     // clamp: only masked-token region affected
        xv[v][k] = x[((size_t)(b * V_ + v) << 12) + s];
      }
    }
#pragma unroll
    for (int dd = 0; dd < 8; ++dd) {
      const int d = dg * 8 + dd;
      const float bb = b1[d];
      float acc[5];
#pragma unroll
      for (int k = 0; k < 5; ++k) acc[k] = bb;
#pragma unroll
      for (int v = 0; v < V_; ++v) {
        const float w = W1[v * E_ + d];
#pragma unroll
        for (int k = 0; k < 5; ++k) acc[k] += xv[v][k] * w;
      }
#pragma unroll
      for (int k = 0; k < 5; ++k)
        et[d * SLP + sg + 32 * k] = (bf16_t)floorf(acc[k]);
    }
  }
  __syncthreads();
  // ---- K-loop: A from LDS e-tile, B streamed from w2sw (L2). d = kk exactly. ----
  const int lane = tid & 63;
  const int wv = tid >> 6;
  const int nh = wv & 1;                // n-half
  const int kh = wv >> 1;               // K-half
  const int l31 = lane & 31;
  const int g = lane >> 5;              // 0/1
  const char* etb = reinterpret_cast<const char*>(et);
  // A-frag: row m = l31 (token), k = 8g + j -> e[d][s_local = 4*l31 + 8g + j]
  const uint32_t aoff = 8u * l31 + 16u * g + 400u * (kh * 32);   // +400 per kkl
  const bf16_t* bptr = w2sw + ((size_t)kh * 32768 + nh * 512 + lane * 8);  // +1024 per kkl
  f32x16 acc = {};
#pragma unroll 8
  for (int kkl = 0; kkl < 32; ++kkl) {
    const char* pa = etb + aoff + 400u * kkl;
    union { uint64_t q[2]; bf16x8 v; } A;
    A.q[0] = *reinterpret_cast<const uint64_t*>(pa);
    A.q[1] = *reinterpret_cast<const uint64_t*>(pa + 8);
    const bf16x8 Bf = *reinterpret_cast<const bf16x8*>(bptr + ((size_t)kkl << 10));
    acc = __builtin_amdgcn_mfma_f32_32x32x16_bf16(A.v, Bf, acc, 0, 0, 0);
  }
  // ---- kh-pair reduction via LDS (transposed: conflict-free b32) ----
  __syncthreads();
  float* red = reinterpret_cast<float*>(et);
  if (kh == 1) {
#pragma unroll
    for (int r = 0; r < 16; ++r) red[r * 128 + nh * 64 + lane] = acc[r];
  }
  __syncthreads();
  if (kh == 0) {
    const float bv = b2[nh * 32 + l31];
#pragma unroll
    for (int r = 0; r < 16; ++r) acc[r] += red[r * 128 + nh * 64 + lane];
    // ---- epilogue: D row = (r&3) + 8*(r>>2) + 4*g (token), col = l31 (n) ----
#pragma unroll
    for (int q4 = 0; q4 < 4; ++q4) {
#pragma unroll
      for (int rr = 0; rr < 4; ++rr) {
        const int row = q4 * 8 + rr + 4 * g;
        const int t = t0 + row;
        if (t < T_)
          out[((size_t)(b * T_ + t)) * E_ + nh * 32 + l31] = floorf(acc[q4 * 4 + rr] + bv);
      }
    }
  }
}

extern "C" void kernel_launch(void* const* d_in, const int* in_sizes, int n_in,
                              void* d_out, int out_size, void* d_ws, size_t ws_size,
                              hipStream_t stream) {
  const float* x  = (const float*)d_in[0];
  const float* W1 = (const float*)d_in[1];
  const float* b1 = (const float*)d_in[2];
  const float* W2 = (const float*)d_in[3];
  const float* b2 = (const float*)d_in[4];
  float* out = (float*)d_out;

  bf16_t* w2sw = (bf16_t*)d_ws;   // 128 KiB swizzled bf16 W2

  hipLaunchKernelGGL(prep_kernel, dim3(32), dim3(256), 0, stream, W2, w2sw);
  hipLaunchKernelGGL(fused_kernel, dim3((T_ + TT - 1) / TT, B_), dim3(256), 0, stream,
                     x, W1, b1, w2sw, b2, out);
}